// Round 1
// baseline (1409.472 us; speedup 1.0000x reference)
//
#include <hip/hip_runtime.h>

// GlobalRankPooling: out[b,c] = sum_s sort_desc(x[b,c,:])[s] * w[c,s] + bias[c]
// B=32, C=2048, S=1024. One 256-thread block per (b,c) pair; in-LDS bitonic sort.

#define C_DIM 2048
#define S_DIM 1024

__global__ __launch_bounds__(256) void rankpool_bitonic_kernel(
    const float* __restrict__ x, const float* __restrict__ w,
    const float* __restrict__ bias, float* __restrict__ out) {
  __shared__ float buf[S_DIM];
  __shared__ float red[4];

  const int bc = blockIdx.x;           // b*C + c
  const int c  = bc & (C_DIM - 1);
  const int t  = threadIdx.x;

  // ---- load 1024 floats, vectorized (16B/lane, coalesced) ----
  const float4* xp4 = (const float4*)(x + (size_t)bc * S_DIM);
  ((float4*)buf)[t] = xp4[t];
  __syncthreads();

  // ---- bitonic sort, descending ----
  for (int k = 2; k <= S_DIM; k <<= 1) {
    for (int j = k >> 1; j > 0; j >>= 1) {
      #pragma unroll
      for (int q = 0; q < 4; ++q) {
        const int i = t + q * 256;
        const int l = i ^ j;
        if (l > i) {  // this thread owns the compare-exchange for pair (i,l)
          const float a = buf[i];
          const float b = buf[l];
          // (i & k) == 0  -> this k-block merges descending (larger at i)
          const bool up = ((i & k) == 0);
          const bool doswap = up ? (a < b) : (a > b);
          if (doswap) { buf[i] = b; buf[l] = a; }
        }
      }
      __syncthreads();
    }
  }

  // ---- dot with weight row (coalesced; w[c] reused by 32 blocks via L2/L3) ----
  const float* wp = w + (size_t)c * S_DIM;
  float acc = 0.f;
  #pragma unroll
  for (int q = 0; q < 4; ++q) {
    const int i = t + q * 256;
    acc += buf[i] * wp[i];
  }

  // wave reduction (wave64)
  #pragma unroll
  for (int off = 32; off > 0; off >>= 1)
    acc += __shfl_down(acc, off, 64);
  if ((t & 63) == 0) red[t >> 6] = acc;
  __syncthreads();

  if (t == 0) {
    out[bc] = red[0] + red[1] + red[2] + red[3] + bias[c];
  }
}

extern "C" void kernel_launch(void* const* d_in, const int* in_sizes, int n_in,
                              void* d_out, int out_size, void* d_ws, size_t ws_size,
                              hipStream_t stream) {
  const float* x    = (const float*)d_in[0];   // (32, 2048, 32, 32) f32
  const float* w    = (const float*)d_in[1];   // (2048, 1, 1024)   f32
  const float* bias = (const float*)d_in[2];   // (2048,)           f32
  float* out        = (float*)d_out;           // (32, 2048, 1)     f32

  const int n_blocks = 32 * C_DIM;             // one block per (b,c)
  rankpool_bitonic_kernel<<<n_blocks, 256, 0, stream>>>(x, w, bias, out);
}

// Round 3
// 521.296 us; speedup vs baseline: 2.7038x; 2.7038x over previous
//
#include <hip/hip_runtime.h>

// GlobalRankPooling: out[b,c] = sum_s sort_desc(x[b,c,:])[s] * w[c,s] + bias[c]
// B=32, C=2048, S=1024.
// One WAVE (64 lanes) per (b,c) pair; 16 elements per lane, virtual index
// i = 16*lane + q. Entire bitonic sort in registers + __shfl_xor:
//   j >= 16 : cross-lane shuffle with lane ^ (j>>4)   (21 steps)
//   j <  16 : in-register compare-exchange            (34 steps)
// NO LDS arrays, NO __syncthreads -> no cross-launch state, race-impossible.

#define C_DIM 2048
#define S_DIM 1024

__global__ __launch_bounds__(256) void rankpool_wave_kernel(
    const float* __restrict__ x, const float* __restrict__ w,
    const float* __restrict__ bias, float* __restrict__ out) {
  const int t    = threadIdx.x;
  const int wid  = t >> 6;                   // wave id within block (0..3)
  const int lane = t & 63;
  const int bc   = (blockIdx.x << 2) | wid;  // one wave per (b,c)
  const int c    = bc & (C_DIM - 1);

  // ---- load 16 elems/lane, perfectly coalesced float4 ----
  // Initial permutation is irrelevant (we sort), so any reg slot works.
  float r[16];
  {
    const float4* x4 = (const float4*)(x + (size_t)bc * S_DIM);
    #pragma unroll
    for (int q2 = 0; q2 < 4; ++q2) {
      const float4 v = x4[(q2 << 6) + lane];
      r[4 * q2 + 0] = v.x; r[4 * q2 + 1] = v.y;
      r[4 * q2 + 2] = v.z; r[4 * q2 + 3] = v.w;
    }
  }

  // ---- bitonic sort over i = 16*lane + q, descending (desc iff (i&k)==0) ----
  #pragma unroll
  for (int k = 2; k <= S_DIM; k <<= 1) {
    #pragma unroll
    for (int j = k >> 1; j > 0; j >>= 1) {
      if (j >= 16) {
        // cross-lane: partner lane = lane ^ (j>>4); same q.
        // i&j -> lane bit (j>>4); i&k -> lane bit (k>>4) [k=1024 -> 0, desc].
        const int  xl      = j >> 4;
        const bool takemax = ((lane & xl) == 0) == ((lane & (k >> 4)) == 0);
        #pragma unroll
        for (int q = 0; q < 16; ++q) {
          const float p = __shfl_xor(r[q], xl, 64);
          r[q] = takemax ? fmaxf(r[q], p) : fminf(r[q], p);
        }
      } else {
        // in-register CE on pairs (q, q^j)
        #pragma unroll
        for (int q = 0; q < 16; ++q) {
          const int l = q ^ j;
          if (l > q) {
            const bool desc = (k >= 16) ? ((lane & (k >> 4)) == 0)
                                        : ((q & k) == 0);
            const float a = r[q], b = r[l];
            const float hi = fmaxf(a, b), lo = fminf(a, b);
            r[q] = desc ? hi : lo;
            r[l] = desc ? lo : hi;
          }
        }
      }
    }
  }

  // ---- dot with weight row: lane holds sorted[16*lane .. 16*lane+15] ----
  const float4* w4 = (const float4*)(w + (size_t)c * S_DIM);
  float acc = 0.f;
  #pragma unroll
  for (int q2 = 0; q2 < 4; ++q2) {
    const float4 wv = w4[(lane << 2) + q2];
    acc += r[4 * q2 + 0] * wv.x + r[4 * q2 + 1] * wv.y +
           r[4 * q2 + 2] * wv.z + r[4 * q2 + 3] * wv.w;
  }

  // wave64 reduction; lane 0 writes
  #pragma unroll
  for (int off = 32; off > 0; off >>= 1)
    acc += __shfl_down(acc, off, 64);
  if (lane == 0) out[bc] = acc + bias[c];
}

extern "C" void kernel_launch(void* const* d_in, const int* in_sizes, int n_in,
                              void* d_out, int out_size, void* d_ws, size_t ws_size,
                              hipStream_t stream) {
  const float* x    = (const float*)d_in[0];   // (32, 2048, 32, 32) f32
  const float* w    = (const float*)d_in[1];   // (2048, 1, 1024)   f32
  const float* bias = (const float*)d_in[2];   // (2048,)           f32
  float* out        = (float*)d_out;           // (32, 2048, 1)     f32

  // 65536 pairs, 4 waves (pairs) per 256-thread block
  rankpool_wave_kernel<<<(32 * C_DIM) / 4, 256, 0, stream>>>(x, w, bias, out);
}

// Round 4
// 512.197 us; speedup vs baseline: 2.7518x; 1.0178x over previous
//
#include <hip/hip_runtime.h>

// GlobalRankPooling: out[b,c] = sum_s sort_desc(x[b,c,:])[s] * w[c,s] + bias[c]
// B=32, C=2048, S=1024. One wave per (b,c), 16 elems/lane, i = 16*lane + q.
// Round-4: sign-space bitonic (all in-register CEs have compile-time direction,
// 2 VALU each) + DPP lane swaps for xor in {1,2,8} (VALU pipe, no DS).
// Zero LDS, zero barriers.

#define C_DIM 2048
#define S_DIM 1024

__device__ __forceinline__ float fxor(float v, unsigned m) {
  return __int_as_float(__float_as_int(v) ^ (int)m);
}

template <int CTRL>
__device__ __forceinline__ float dpp_swap(float v) {
  return __int_as_float(__builtin_amdgcn_update_dpp(
      0, __float_as_int(v), CTRL, 0xF, 0xF, false));
}

// One cross-lane CE step in adjusted (sign-absorbed) space: partner = lane^JL,
// lane with (lane & JL)==0 keeps elementwise max, other keeps min.
// Moves happen with ALL lanes active (DPP/permute under exec-mask is undefined);
// only pure-VALU min/max sits under the divergent branch.
template <int JL>
__device__ __forceinline__ void cross_step(float (&r)[16], int lane) {
  float p[16];
  #pragma unroll
  for (int q = 0; q < 16; ++q) {
    if      (JL == 1) p[q] = dpp_swap<0xB1>(r[q]);   // quad_perm(1,0,3,2) = xor1
    else if (JL == 2) p[q] = dpp_swap<0x4E>(r[q]);   // quad_perm(2,3,0,1) = xor2
    else if (JL == 8) p[q] = dpp_swap<0x128>(r[q]);  // row_ror:8 == xor8 in 16-row
    else              p[q] = __shfl_xor(r[q], JL, 64); // xor 4 / 16 / 32
  }
  if ((lane & JL) == 0) {
    #pragma unroll
    for (int q = 0; q < 16; ++q) r[q] = fmaxf(r[q], p[q]);
  } else {
    #pragma unroll
    for (int q = 0; q < 16; ++q) r[q] = fminf(r[q], p[q]);
  }
}

// In-register bitonic merge steps j=8,4,2,1 in adjusted space:
// lower register index always takes max (compile-time direction).
__device__ __forceinline__ void local_merge16(float (&r)[16]) {
  #pragma unroll
  for (int j = 8; j >= 1; j >>= 1) {
    #pragma unroll
    for (int q = 0; q < 16; ++q) {
      const int l = q ^ j;
      if (l > q) {
        const float hi = fmaxf(r[q], r[l]);
        const float lo = fminf(r[q], r[l]);
        r[q] = hi; r[l] = lo;
      }
    }
  }
}

__device__ __forceinline__ void flip_all(float (&r)[16], unsigned bit) {
  const unsigned m = bit << 31;   // 0 or 0x80000000
  #pragma unroll
  for (int q = 0; q < 16; ++q) r[q] = fxor(r[q], m);
}

__global__ __launch_bounds__(256) void rankpool_dpp_kernel(
    const float* __restrict__ x, const float* __restrict__ w,
    const float* __restrict__ bias, float* __restrict__ out) {
  const int t    = threadIdx.x;
  const int wid  = t >> 6;
  const int lane = t & 63;
  const int bc   = (blockIdx.x << 2) | wid;  // one wave per (b,c)
  const int c    = bc & (C_DIM - 1);

  // ---- load 16 elems/lane (any initial permutation is fine — we sort) ----
  float r[16];
  {
    const float4* x4 = (const float4*)(x + (size_t)bc * S_DIM);
    #pragma unroll
    for (int q2 = 0; q2 < 4; ++q2) {
      const float4 v = x4[(q2 << 6) + lane];
      r[4 * q2 + 0] = v.x; r[4 * q2 + 1] = v.y;
      r[4 * q2 + 2] = v.z; r[4 * q2 + 3] = v.w;
    }
  }

  // ---- stages k=2,4,8: in-register, raw space, compile-time directions ----
  #pragma unroll
  for (int k = 2; k <= 8; k <<= 1) {
    #pragma unroll
    for (int j = k >> 1; j >= 1; j >>= 1) {
      #pragma unroll
      for (int q = 0; q < 16; ++q) {
        const int l = q ^ j;
        if (l > q) {
          const bool desc = ((q & k) == 0);
          const float hi = fmaxf(r[q], r[l]);
          const float lo = fminf(r[q], r[l]);
          r[q] = desc ? hi : lo;   // compile-time select
          r[l] = desc ? lo : hi;
        }
      }
    }
  }

  // desc_k(lane) = ((lane & (k>>4)) == 0). Enter adjusted space for k=16:
  flip_all(r, lane & 1u);

  // ---- stage k=16 (in-reg only) ----
  local_merge16(r);
  flip_all(r, ((lane >> 0) ^ (lane >> 1)) & 1u);
  // ---- k=32 ----
  cross_step<1>(r, lane);
  local_merge16(r);
  flip_all(r, ((lane >> 1) ^ (lane >> 2)) & 1u);
  // ---- k=64 ----
  cross_step<2>(r, lane); cross_step<1>(r, lane);
  local_merge16(r);
  flip_all(r, ((lane >> 2) ^ (lane >> 3)) & 1u);
  // ---- k=128 ----
  cross_step<4>(r, lane); cross_step<2>(r, lane); cross_step<1>(r, lane);
  local_merge16(r);
  flip_all(r, ((lane >> 3) ^ (lane >> 4)) & 1u);
  // ---- k=256 ----
  cross_step<8>(r, lane); cross_step<4>(r, lane); cross_step<2>(r, lane);
  cross_step<1>(r, lane);
  local_merge16(r);
  flip_all(r, ((lane >> 4) ^ (lane >> 5)) & 1u);
  // ---- k=512 ----
  cross_step<16>(r, lane); cross_step<8>(r, lane); cross_step<4>(r, lane);
  cross_step<2>(r, lane);  cross_step<1>(r, lane);
  local_merge16(r);
  flip_all(r, ((lane >> 5) ^ (lane >> 6)) & 1u);
  // ---- k=1024 (desc for all lanes -> adjusted space == raw space) ----
  cross_step<32>(r, lane); cross_step<16>(r, lane); cross_step<8>(r, lane);
  cross_step<4>(r, lane);  cross_step<2>(r, lane);  cross_step<1>(r, lane);
  local_merge16(r);

  // ---- dot with weight row: lane holds sorted[16*lane .. 16*lane+15] ----
  const float4* w4 = (const float4*)(w + (size_t)c * S_DIM);
  float acc = 0.f;
  #pragma unroll
  for (int q2 = 0; q2 < 4; ++q2) {
    const float4 wv = w4[(lane << 2) + q2];
    acc += r[4 * q2 + 0] * wv.x + r[4 * q2 + 1] * wv.y +
           r[4 * q2 + 2] * wv.z + r[4 * q2 + 3] * wv.w;
  }

  #pragma unroll
  for (int off = 32; off > 0; off >>= 1)
    acc += __shfl_down(acc, off, 64);
  if (lane == 0) out[bc] = acc + bias[c];
}

extern "C" void kernel_launch(void* const* d_in, const int* in_sizes, int n_in,
                              void* d_out, int out_size, void* d_ws, size_t ws_size,
                              hipStream_t stream) {
  const float* x    = (const float*)d_in[0];   // (32, 2048, 32, 32) f32
  const float* w    = (const float*)d_in[1];   // (2048, 1, 1024)   f32
  const float* bias = (const float*)d_in[2];   // (2048,)           f32
  float* out        = (float*)d_out;           // (32, 2048, 1)     f32

  rankpool_dpp_kernel<<<(32 * C_DIM) / 4, 256, 0, stream>>>(x, w, bias, out);
}

// Round 5
// 504.545 us; speedup vs baseline: 2.7936x; 1.0152x over previous
//
#include <hip/hip_runtime.h>

// GlobalRankPooling: out[b,c] = sum_s sort_desc(x[b,c,:])[s] * w[c,s] + bias[c]
// B=32, C=2048, S=1024. One wave per (b,c), 16 elems/lane, i = 16*lane + q.
// Round-5: DUAL sign-space bitonic — every cross-lane CE is exactly
//   p = move(r);  r = v_max_f32(r, -p)     (modifier-negate, branchless)
// for ALL lanes. Lane moves: DPP (xor 1/2/8), ds_swizzle (xor 4/16),
// ds_bpermute (xor 32). Convention flips are single v_xor_b32 per element
// with single-lane-bit masks. Zero LDS arrays, zero barriers, zero branches.

#define C_DIM 2048
#define S_DIM 1024

template <int CTRL>
__device__ __forceinline__ float dppf(float v) {
  return __int_as_float(__builtin_amdgcn_update_dpp(
      0, __float_as_int(v), CTRL, 0xF, 0xF, false));
}
template <int PAT>
__device__ __forceinline__ float swzf(float v) {
  return __int_as_float(__builtin_amdgcn_ds_swizzle(__float_as_int(v), PAT));
}
__device__ __forceinline__ float bperm(int addr, float v) {
  return __int_as_float(__builtin_amdgcn_ds_bpermute(addr, __float_as_int(v)));
}

// One cross-lane CE step in dual-adjusted space: r = max(r, -p), all lanes.
template <int JL>
__device__ __forceinline__ void cross(float (&r)[16], int addr32) {
  float p[16];
  #pragma unroll
  for (int q = 0; q < 16; ++q) {
    if      (JL == 1)  p[q] = dppf<0xB1>(r[q]);    // quad_perm(1,0,3,2)
    else if (JL == 2)  p[q] = dppf<0x4E>(r[q]);    // quad_perm(2,3,0,1)
    else if (JL == 4)  p[q] = swzf<0x101F>(r[q]);  // BitMode xor4
    else if (JL == 8)  p[q] = dppf<0x128>(r[q]);   // row_ror:8 == xor8
    else if (JL == 16) p[q] = swzf<0x401F>(r[q]);  // BitMode xor16
    else               p[q] = bperm(addr32, r[q]); // xor32
  }
  #pragma unroll
  for (int q = 0; q < 16; ++q) r[q] = fmaxf(r[q], -p[q]);  // neg = free modifier
}

// In-register bitonic merge j=8,4,2,1; lower reg index takes max.
__device__ __forceinline__ void merge16(float (&r)[16]) {
  #pragma unroll
  for (int j = 8; j >= 1; j >>= 1) {
    #pragma unroll
    for (int q = 0; q < 16; ++q) {
      const int l = q ^ j;
      if (l > q) {
        const float hi = fmaxf(r[q], r[l]);
        const float lo = fminf(r[q], r[l]);
        r[q] = hi; r[l] = lo;
      }
    }
  }
}

__device__ __forceinline__ void flip(float (&r)[16], unsigned m) {
  #pragma unroll
  for (int q = 0; q < 16; ++q)
    r[q] = __int_as_float(__float_as_int(r[q]) ^ (int)m);
}

__global__ __launch_bounds__(256) void rankpool_signspace_kernel(
    const float* __restrict__ x, const float* __restrict__ w,
    const float* __restrict__ bias, float* __restrict__ out) {
  const int t      = threadIdx.x;
  const int lane   = t & 63;
  const int bc     = (blockIdx.x << 2) | (t >> 6);   // one wave per (b,c)
  const int c      = bc & (C_DIM - 1);
  const int addr32 = (lane ^ 32) << 2;               // bpermute byte address
  const unsigned L = (unsigned)lane;
  #define MB(b)      ((L << (31 - (b))) & 0x80000000u)             // lane bit b
  #define MX(bi, bj) (((L << (31-(bi))) ^ (L << (31-(bj)))) & 0x80000000u)

  // ---- load 16 elems/lane (initial permutation irrelevant — we sort) ----
  float r[16];
  {
    const float4* x4 = (const float4*)(x + (size_t)bc * S_DIM);
    #pragma unroll
    for (int q2 = 0; q2 < 4; ++q2) {
      const float4 v = x4[(q2 << 6) + lane];
      r[4*q2+0] = v.x; r[4*q2+1] = v.y; r[4*q2+2] = v.z; r[4*q2+3] = v.w;
    }
  }

  // ---- stages k=2,4,8: in-register, raw space, compile-time directions ----
  #pragma unroll
  for (int k = 2; k <= 8; k <<= 1) {
    #pragma unroll
    for (int j = k >> 1; j >= 1; j >>= 1) {
      #pragma unroll
      for (int q = 0; q < 16; ++q) {
        const int l = q ^ j;
        if (l > q) {
          const bool desc = ((q & k) == 0);
          const float hi = fmaxf(r[q], r[l]);
          const float lo = fminf(r[q], r[l]);
          r[q] = desc ? hi : lo;   // compile-time select
          r[l] = desc ? lo : hi;
        }
      }
    }
  }

  // ---- k=16: enter W16 (flip bit0 lanes), in-register merge ----
  flip(r, MB(0));
  merge16(r);

  // ---- k=32 ----   boundary(b0^b1) ⊕ enterD(b0) = b1
  flip(r, MB(1));
  cross<1>(r, addr32);
  flip(r, MB(0));                       // exit D
  merge16(r);

  // ---- k=64 ----   boundary(b1^b2) ⊕ enterD(b1) = b2
  flip(r, MB(2));
  cross<2>(r, addr32);
  flip(r, MX(1, 0));                    // D=2 -> D=1
  cross<1>(r, addr32);
  flip(r, MB(0));
  merge16(r);

  // ---- k=128 ----  boundary(b2^b3) ⊕ enterD(b2) = b3
  flip(r, MB(3));
  cross<4>(r, addr32);
  flip(r, MX(2, 1));
  cross<2>(r, addr32);
  flip(r, MX(1, 0));
  cross<1>(r, addr32);
  flip(r, MB(0));
  merge16(r);

  // ---- k=256 ----  boundary(b3^b4) ⊕ enterD(b3) = b4
  flip(r, MB(4));
  cross<8>(r, addr32);
  flip(r, MX(3, 2));
  cross<4>(r, addr32);
  flip(r, MX(2, 1));
  cross<2>(r, addr32);
  flip(r, MX(1, 0));
  cross<1>(r, addr32);
  flip(r, MB(0));
  merge16(r);

  // ---- k=512 ----  boundary(b4^b5) ⊕ enterD(b4) = b5
  flip(r, MB(5));
  cross<16>(r, addr32);
  flip(r, MX(4, 3));
  cross<8>(r, addr32);
  flip(r, MX(3, 2));
  cross<4>(r, addr32);
  flip(r, MX(2, 1));
  cross<2>(r, addr32);
  flip(r, MX(1, 0));
  cross<1>(r, addr32);
  flip(r, MB(0));
  merge16(r);

  // ---- k=1024 ---- boundary(b5^b6=b5) ⊕ enterD(b5) = 0 (no flip)
  cross<32>(r, addr32);
  flip(r, MX(5, 4));
  cross<16>(r, addr32);
  flip(r, MX(4, 3));
  cross<8>(r, addr32);
  flip(r, MX(3, 2));
  cross<4>(r, addr32);
  flip(r, MX(2, 1));
  cross<2>(r, addr32);
  flip(r, MX(1, 0));
  cross<1>(r, addr32);
  flip(r, MB(0));
  merge16(r);                           // raw space, fully descending

  // ---- dot with weight row: lane holds sorted[16*lane .. 16*lane+15] ----
  const float4* w4 = (const float4*)(w + (size_t)c * S_DIM);
  float acc = 0.f;
  #pragma unroll
  for (int q2 = 0; q2 < 4; ++q2) {
    const float4 wv = w4[(lane << 2) + q2];
    acc += r[4*q2+0] * wv.x + r[4*q2+1] * wv.y +
           r[4*q2+2] * wv.z + r[4*q2+3] * wv.w;
  }

  // ---- butterfly wave reduction (same single-inst movers) ----
  acc += dppf<0xB1>(acc);
  acc += dppf<0x4E>(acc);
  acc += swzf<0x101F>(acc);
  acc += dppf<0x128>(acc);
  acc += swzf<0x401F>(acc);
  acc += bperm(addr32, acc);
  if (lane == 0) out[bc] = acc + bias[c];

  #undef MB
  #undef MX
}

extern "C" void kernel_launch(void* const* d_in, const int* in_sizes, int n_in,
                              void* d_out, int out_size, void* d_ws, size_t ws_size,
                              hipStream_t stream) {
  const float* x    = (const float*)d_in[0];   // (32, 2048, 32, 32) f32
  const float* w    = (const float*)d_in[1];   // (2048, 1, 1024)   f32
  const float* bias = (const float*)d_in[2];   // (2048,)           f32
  float* out        = (float*)d_out;           // (32, 2048, 1)     f32

  rankpool_signspace_kernel<<<(32 * C_DIM) / 4, 256, 0, stream>>>(x, w, bias, out);
}